// Round 3
// baseline (113.081 us; speedup 1.0000x reference)
//
#include <hip/hip_runtime.h>

// Always (smoothed-min sliding window, W=16) over [B,T,D] fp32, two traces.
// out[b,t,d] = -log( sum_{j=0..15} exp(-5 x[b, max(t-15+j,0), d]) ) / 5
//
// R9: dwordx4 everywhere. R8 post-mortem: kernel <42.4us (masked by the
// 42.5us poison-fills in top-5), ~2.5 TB/s. Decisive datapoint: the fill
// kernel hits 6.3 TB/s at 8 VGPR / 8.7% occupancy with dwordx4 stores,
// and the 6.29 TB/s copy ceiling (m13) is float4. TLP is not our limiter;
// 4B/lane access width is (4x VMEM instrs, 4x per-request TA/TCC cost).
// New layout: wave = one seq strip of 64 t. lane = (st, dq):
//   st = lane>>4 : owns 4 CONSECUTIVE t-steps (tb+4st .. tb+4st+3)
//   dq = lane&15 : owns channels 4dq..4dq+3  -> every load/store dwordx4.
// Window sum = suffix(prev block) + prefix(cur block), now via a 4-group
// cross-lane scan (shfl_up/down dist 16/32) -- ADDITIONS OF POSITIVES ONLY
// (exclusive scans built by shifted adds; no big-minus-big cancellation).
// Halo-exp reuse kept: carry Sc[k] = suffix-from-pos(4st+k+1) of the
// previous block, exactly what the next block's lane (st,k) needs.

#define TT     8192
#define DD     64
#define STRIPS 128           // strips per seq
#define SLEN   (TT / STRIPS) // 64 t-steps per wave

typedef float vfloat4 __attribute__((ext_vector_type(4)));

__device__ __forceinline__ float4 add4(float4 a, float4 b) {
    return make_float4(a.x + b.x, a.y + b.y, a.z + b.z, a.w + b.w);
}
__device__ __forceinline__ float4 exp4n(float4 v) {
    float4 r;
    r.x = __expf(-5.0f * v.x);
    r.y = __expf(-5.0f * v.y);
    r.z = __expf(-5.0f * v.z);
    r.w = __expf(-5.0f * v.w);
    return r;
}
__device__ __forceinline__ vfloat4 mlog4(float4 v) {
    vfloat4 r;
    r.x = -0.2f * __logf(v.x);
    r.y = -0.2f * __logf(v.y);
    r.z = -0.2f * __logf(v.z);
    r.w = -0.2f * __logf(v.w);
    return r;
}
__device__ __forceinline__ float4 shflu(float4 v, int d) {
    float4 r;
    r.x = __shfl_up(v.x, d); r.y = __shfl_up(v.y, d);
    r.z = __shfl_up(v.z, d); r.w = __shfl_up(v.w, d);
    return r;
}
__device__ __forceinline__ float4 shfld(float4 v, int d) {
    float4 r;
    r.x = __shfl_down(v.x, d); r.y = __shfl_down(v.y, d);
    r.z = __shfl_down(v.z, d); r.w = __shfl_down(v.w, d);
    return r;
}
#define Z4 make_float4(0.f, 0.f, 0.f, 0.f)

struct Carry { float4 s[4]; };   // s[k] = suffix of prev block from pos 4st+k+1

// Reverse (suffix) part shared by halo and full blocks. R[] must already be
// exp'd. Computes the carry for the NEXT block. All shuffles run full-wave;
// validity handled by selects (no divergence).
__device__ __forceinline__ void make_carry(const float4 R[4], int st, Carry& c) {
    const float4 q3 = R[3];
    const float4 q2 = add4(R[2], q3);
    const float4 q1 = add4(R[1], q2);
    const float4 q0 = add4(R[0], q1);            // rtot = suffix of own 4
    const float4 rc_raw = shfld(q0, 16);         // rtot[st+1]
    const float4 rc = (st <= 2) ? rc_raw : Z4;
    const float4 rd_raw = shfld(add4(rc, q0), 32); // rtot[st+2]+rtot[st+3]
    const float4 rex = add4(rc, (st <= 1) ? rd_raw : Z4); // sum of groups > st
    c.s[0] = add4(q1, rex);
    c.s[1] = add4(q2, rex);
    c.s[2] = add4(q3, rex);
    const float4 rinc = add4(q0, rex);           // suffix from pos 4st
    const float4 c3_raw = shfld(rinc, 16);       // suffix from pos 4(st+1)
    c.s[3] = (st <= 2) ? c3_raw : Z4;
}

// One 16-step output block: raw R -> exp -> outputs via carry+prefix-scan,
// then replace carry with this block's suffix info.
__device__ __forceinline__ void block_out(float4 R[4], Carry& c, int st,
                                          float* __restrict__ dst, int tb) {
    #pragma unroll
    for (int k = 0; k < 4; ++k) R[k] = exp4n(R[k]);
    // forward prefix within lane
    const float4 p0 = R[0];
    const float4 p1 = add4(p0, R[1]);
    const float4 p2 = add4(p1, R[2]);
    const float4 p3 = add4(p2, R[3]);            // tot of own 4
    // exclusive scan of tot across st groups (additions only)
    const float4 cu_raw = shflu(p3, 16);         // tot[st-1]
    const float4 cu = (st >= 1) ? cu_raw : Z4;
    const float4 du_raw = shflu(add4(cu, p3), 32); // tot[st-3]+tot[st-2]
    const float4 ex = add4(cu, (st >= 2) ? du_raw : Z4);
    // window sums: W[k] = suffix_prev(4st+k+1) + (ex + p[k])
    const float4 W0 = add4(c.s[0], add4(ex, p0));
    const float4 W1 = add4(c.s[1], add4(ex, p1));
    const float4 W2 = add4(c.s[2], add4(ex, p2));
    const float4 W3 = add4(c.s[3], add4(ex, p3));
    // carry for next block (reads R only; c safe to overwrite now)
    make_carry(R, st, c);
    // NT dwordx4 stores: t = tb + 4*st + k
    vfloat4* __restrict__ d0 = (vfloat4*)(dst + (size_t)(tb + 4 * st) * DD);
    __builtin_nontemporal_store(mlog4(W0), d0);
    __builtin_nontemporal_store(mlog4(W1), d0 + DD / 4);
    __builtin_nontemporal_store(mlog4(W2), d0 + 2 * (DD / 4));
    __builtin_nontemporal_store(mlog4(W3), d0 + 3 * (DD / 4));
}

__global__ __launch_bounds__(256, 4) void always_minish_v9(
    const float* __restrict__ lower,
    const float* __restrict__ upper,
    float* __restrict__ out)
{
    const int lane  = threadIdx.x & 63;
    const int dq    = lane & 15;           // channel quad 4dq..4dq+3
    const int st    = lane >> 4;           // t-subgroup 0..3 (4 consecutive t)
    const int wv    = (blockIdx.x << 2) | (threadIdx.x >> 6);
    const int seq   = wv >> 7;             // 0..31 = trace*16 + b
    const int strip = wv & (STRIPS - 1);   // 0..127
    const int tr    = seq >> 4;
    const int b     = seq & 15;

    const float4* __restrict__ srcv =
        (const float4*)((tr ? upper : lower) + (size_t)b * TT * DD) + dq;
    float* __restrict__ dst = out + (size_t)seq * TT * DD + dq * 4;

    const int t0 = strip * SLEN;

    float4 A[4], B[4], C[4];
    Carry c;

    // Halo block t0-16..t0-1 (clamped to 0 == h0 broadcast semantics).
    #pragma unroll
    for (int k = 0; k < 4; ++k) {
        int t = t0 - 16 + 4 * st + k;
        if (t < 0) t = 0;
        A[k] = *((const float4*)((const float*)0 + 0) , &srcv[(size_t)t * (DD / 4)]);
    }
    // Blocks 0 and 1 raw.
    #pragma unroll
    for (int k = 0; k < 4; ++k) B[k] = srcv[(size_t)(t0 + 4 * st + k) * (DD / 4)];
    #pragma unroll
    for (int k = 0; k < 4; ++k) C[k] = srcv[(size_t)(t0 + 16 + 4 * st + k) * (DD / 4)];

    // Halo: exp + carry only (no outputs). A becomes free after this.
    #pragma unroll
    for (int k = 0; k < 4; ++k) A[k] = exp4n(A[k]);
    make_carry(A, st, c);

    // Prefetch block 2 into A under block-0 compute.
    #pragma unroll
    for (int k = 0; k < 4; ++k) A[k] = srcv[(size_t)(t0 + 32 + 4 * st + k) * (DD / 4)];
    block_out(B, c, st, dst, t0);

    // Prefetch block 3 into B under block-1 compute.
    #pragma unroll
    for (int k = 0; k < 4; ++k) B[k] = srcv[(size_t)(t0 + 48 + 4 * st + k) * (DD / 4)];
    block_out(C, c, st, dst, t0 + 16);

    block_out(A, c, st, dst, t0 + 32);
    block_out(B, c, st, dst, t0 + 48);
}

extern "C" void kernel_launch(void* const* d_in, const int* in_sizes, int n_in,
                              void* d_out, int out_size, void* d_ws, size_t ws_size,
                              hipStream_t stream)
{
    const float* lower = (const float*)d_in[0];
    const float* upper = (const float*)d_in[1];
    float* out = (float*)d_out;

    // 32 seq * 128 strips = 4096 waves -> 1024 blocks of 4 waves.
    // Block = 4 consecutive strips of one seq -> 64KB contiguous region.
    dim3 grid(1024), block(256);
    hipLaunchKernelGGL(always_minish_v9, grid, block, 0, stream,
                       lower, upper, out);
}